// Round 11
// baseline (320.233 us; speedup 1.0000x reference)
//
#include <hip/hip_runtime.h>
#include <cstddef>

#define Nn 50000
#define Ee 500000
#define INC 128
#define HC 256      // HEADS*OUT_C
#define OUTC 64
#define EDIM 32
#define NEG 0.2f
#define NB 196      // scan blocks = ceil(Nn/256)

typedef __attribute__((ext_vector_type(8))) short short8;   // 8 bf16 = 4 VGPR
typedef __attribute__((ext_vector_type(4))) float f32x4;

// ---- bf16 helpers (RNE) ----
__device__ __forceinline__ unsigned short f2bf(float f) {
    unsigned u = __float_as_uint(f);
    return (unsigned short)((u + 0x7FFFu + ((u >> 16) & 1u)) >> 16);
}
__device__ __forceinline__ float bf2f(unsigned short v) {
    return __uint_as_float(((unsigned)v) << 16);
}

// ---- 16-lane row sum via DPP butterfly (pure VALU, no DS pipe) ----
__device__ __forceinline__ float row_sum16(float x) {
    int i;
    i = __builtin_amdgcn_mov_dpp(__float_as_int(x), 0xB1, 0xF, 0xF, true);
    x += __int_as_float(i);
    i = __builtin_amdgcn_mov_dpp(__float_as_int(x), 0x4E, 0xF, 0xF, true);
    x += __int_as_float(i);
    i = __builtin_amdgcn_mov_dpp(__float_as_int(x), 0x141, 0xF, 0xF, true);
    x += __int_as_float(i);
    i = __builtin_amdgcn_mov_dpp(__float_as_int(x), 0x140, 0xF, 0xF, true);
    x += __int_as_float(i);
    return x;
}

// ---- K_pack: Wl/Wr (T-perm, for gemm) + We (cb-perm, for edge_alpha) ----
__global__ __launch_bounds__(256) void pack_kernel(
    const float* __restrict__ Wl, const float* __restrict__ Wr,
    const float* __restrict__ We,
    unsigned short* __restrict__ wlf, unsigned short* __restrict__ wrf,
    unsigned short* __restrict__ wef)
{
    int sid = blockIdx.x * 256 + threadIdx.x;
    const float* W; unsigned short* dst; int s; int col; int k0;
    if (sid < 8192) {
        if (sid < 4096) { W = Wl; dst = wlf; s = sid; }
        else            { W = Wr; dst = wrf; s = sid - 4096; }
        int lane = s & 63;
        int T    = (s >> 6) & 15;
        int kc   = s >> 10;
        col = (lane & 15) * 16 + T;
        k0  = kc * 32 + (lane >> 4) * 8;
    } else if (sid < 9216) {
        W = We; dst = wef; s = sid - 8192;
        int lane = s & 63;
        int nt   = (s >> 6) & 3;
        int cb   = s >> 8;
        col = cb * 64 + (lane & 15) * 4 + nt;
        k0  = (lane >> 4) * 8;
    } else return;
    unsigned short tmp[8];
    #pragma unroll
    for (int j = 0; j < 8; ++j) tmp[j] = f2bf(W[(size_t)(k0 + j) * HC + col]);
    *(uint4*)(dst + (size_t)s * 8) = *(uint4*)tmp;
}

// ---- K1: Y = bf16(X @ W + b) via MFMA, no LDS ----
__global__ __launch_bounds__(256) void gemm_kernel(
    const float* __restrict__ X,
    const unsigned short* __restrict__ wlf, const float* __restrict__ bl,
    const unsigned short* __restrict__ wrf, const float* __restrict__ br,
    unsigned short* __restrict__ Ylb, unsigned short* __restrict__ Yrb)
{
    const unsigned short* wf; const float* b; unsigned short* Yb;
    if (blockIdx.y == 0) { wf = wlf; b = bl; Yb = Ylb; } else { wf = wrf; b = br; Yb = Yrb; }

    const int tid = threadIdx.x, lane = tid & 63;
    const int l15 = lane & 15, l4 = lane >> 4;
    const int r0 = blockIdx.x * 64 + (tid >> 6) * 16;

    int arow = r0 + l15; if (arow >= Nn) arow = Nn - 1;
    short8 af[4];
    #pragma unroll
    for (int kc = 0; kc < 4; ++kc) {
        const f32x4* p = (const f32x4*)(X + (size_t)arow * INC + kc * 32 + l4 * 8);
        f32x4 v0 = p[0], v1 = p[1];
        short8 a;
        a[0]=(short)f2bf(v0.x); a[1]=(short)f2bf(v0.y); a[2]=(short)f2bf(v0.z); a[3]=(short)f2bf(v0.w);
        a[4]=(short)f2bf(v1.x); a[5]=(short)f2bf(v1.y); a[6]=(short)f2bf(v1.z); a[7]=(short)f2bf(v1.w);
        af[kc] = a;
    }

    f32x4 acc[16];
    #pragma unroll
    for (int T = 0; T < 16; ++T) acc[T] = (f32x4){0.f, 0.f, 0.f, 0.f};

    #pragma unroll
    for (int kc = 0; kc < 4; ++kc) {
        #pragma unroll
        for (int T = 0; T < 16; ++T) {
            short8 bf = *(const short8*)(wf + ((size_t)(kc * 16 + T) * 64 + lane) * 8);
            acc[T] = __builtin_amdgcn_mfma_f32_16x16x32_bf16(af[kc], bf, acc[T], 0, 0, 0);
        }
    }

    float bb[16];
    #pragma unroll
    for (int t4 = 0; t4 < 4; ++t4) {
        float4 v = *(const float4*)(b + l15 * 16 + t4 * 4);
        bb[t4*4+0]=v.x; bb[t4*4+1]=v.y; bb[t4*4+2]=v.z; bb[t4*4+3]=v.w;
    }

    #pragma unroll
    for (int r = 0; r < 4; ++r) {
        int orow = r0 + l4 * 4 + r;
        if (orow < Nn) {
            unsigned short o[16];
            #pragma unroll
            for (int T = 0; T < 16; ++T) o[T] = f2bf(acc[T][r] + bb[T]);
            *(uint4*)(Yb + (size_t)orow * HC + l15 * 16)     = *(uint4*)(o);
            *(uint4*)(Yb + (size_t)orow * HC + l15 * 16 + 8) = *(uint4*)(o + 8);
        }
    }
}

// ---- CSR build ----
__global__ __launch_bounds__(256) void zero_kernel(int* __restrict__ deg) {
    int i = blockIdx.x * 256 + threadIdx.x;
    if (i < Nn) deg[i] = 0;
}
__global__ __launch_bounds__(256) void hist_kernel(
    const int* __restrict__ ei, int* __restrict__ deg) {
    int e = blockIdx.x * 256 + threadIdx.x;
    if (e < Ee) atomicAdd(deg + ei[Ee + e], 1);
}
__global__ __launch_bounds__(256) void scan1_kernel(
    const int* __restrict__ deg, int* __restrict__ off, int* __restrict__ bsum) {
    __shared__ int s[256];
    int i = blockIdx.x * 256 + threadIdx.x;
    int v = (i < Nn) ? deg[i] : 0;
    s[threadIdx.x] = v;
    __syncthreads();
    #pragma unroll
    for (int d = 1; d < 256; d <<= 1) {
        int t = (threadIdx.x >= d) ? s[threadIdx.x - d] : 0;
        __syncthreads();
        s[threadIdx.x] += t;
        __syncthreads();
    }
    if (i < Nn) off[i] = s[threadIdx.x] - v;
    if (threadIdx.x == 255) bsum[blockIdx.x] = s[255];
}
__global__ __launch_bounds__(256) void scan2_kernel(int* __restrict__ bsum) {
    __shared__ int s[256];
    int v = (threadIdx.x < NB) ? bsum[threadIdx.x] : 0;
    s[threadIdx.x] = v;
    __syncthreads();
    #pragma unroll
    for (int d = 1; d < 256; d <<= 1) {
        int t = (threadIdx.x >= d) ? s[threadIdx.x - d] : 0;
        __syncthreads();
        s[threadIdx.x] += t;
        __syncthreads();
    }
    if (threadIdx.x < NB) bsum[threadIdx.x] = s[threadIdx.x] - v;
}
__global__ __launch_bounds__(256) void scan3_kernel(
    int* __restrict__ off, const int* __restrict__ bsum, int* __restrict__ cur) {
    int i = blockIdx.x * 256 + threadIdx.x;
    if (i < Nn) {
        int o = off[i] + bsum[blockIdx.x];
        off[i] = o;
        cur[i] = o;
    }
}
__global__ __launch_bounds__(256) void scatter_kernel(
    const int* __restrict__ ei, int* __restrict__ cur,
    int* __restrict__ csr_e, int* __restrict__ csr_s) {
    int e = blockIdx.x * 256 + threadIdx.x;
    if (e >= Ee) return;
    int d = ei[Ee + e];
    int pos = atomicAdd(cur + d, 1);
    csr_e[pos] = e;
    csr_s[pos] = ei[e];
}

// ---- K2: per-edge logits via MFMA bf16, no LDS, DPP reduce, NO atomics ----
__global__ __launch_bounds__(256) void edge_alpha_kernel(
    const unsigned short* __restrict__ xlb, const unsigned short* __restrict__ xrb,
    const int* __restrict__ ei, const float* __restrict__ ea,
    const unsigned short* __restrict__ wef, const float* __restrict__ att,
    float* __restrict__ alpha)
{
    const int tid  = threadIdx.x;
    const int lane = tid & 63;
    const int l15  = lane & 15, l4 = lane >> 4;
    const int e0   = blockIdx.x * 128 + (tid >> 6) * 32;

    short8 afrag[2];
    #pragma unroll
    for (int mt = 0; mt < 2; ++mt) {
        int e = e0 + mt * 16 + l15;
        if (e >= Ee) e = Ee - 1;
        const f32x4* p = (const f32x4*)(ea + (size_t)e * EDIM + l4 * 8);
        f32x4 v0 = __builtin_nontemporal_load(p);
        f32x4 v1 = __builtin_nontemporal_load(p + 1);
        short8 a;
        a[0]=(short)f2bf(v0.x); a[1]=(short)f2bf(v0.y); a[2]=(short)f2bf(v0.z); a[3]=(short)f2bf(v0.w);
        a[4]=(short)f2bf(v1.x); a[5]=(short)f2bf(v1.y); a[6]=(short)f2bf(v1.z); a[7]=(short)f2bf(v1.w);
        afrag[mt] = a;
    }

    unsigned soff[8], doff[8];
    #pragma unroll
    for (int mt = 0; mt < 2; ++mt)
        #pragma unroll
        for (int r = 0; r < 4; ++r) {
            int idx = mt * 4 + r;
            int e = e0 + mt * 16 + l4 * 4 + r;
            int ec = (e < Ee) ? e : Ee - 1;
            soff[idx] = (unsigned)ei[ec] * (unsigned)HC;
            doff[idx] = (unsigned)ei[Ee + ec] * (unsigned)HC;
        }

    #pragma unroll 1
    for (int cb = 0; cb < 4; ++cb) {
        short8 bfrag[4];
        #pragma unroll
        for (int nt = 0; nt < 4; ++nt)
            bfrag[nt] = *(const short8*)(wef + ((size_t)(cb * 4 + nt) * 64 + lane) * 8);

        f32x4 acc[2][4];
        const f32x4 z = {0.f, 0.f, 0.f, 0.f};
        #pragma unroll
        for (int mt = 0; mt < 2; ++mt)
            #pragma unroll
            for (int nt = 0; nt < 4; ++nt)
                acc[mt][nt] = __builtin_amdgcn_mfma_f32_16x16x32_bf16(
                    afrag[mt], bfrag[nt], z, 0, 0, 0);

        float4 atv = *(const float4*)(att + cb * 64 + l15 * 4);

        #pragma unroll
        for (int mt = 0; mt < 2; ++mt) {
            #pragma unroll
            for (int r = 0; r < 4; ++r) {
                const int idx = mt * 4 + r;
                const unsigned c = (unsigned)(cb * 64 + l15 * 4);
                ushort4 gl4 = *(const ushort4*)(xlb + soff[idx] + c);
                ushort4 gr4 = *(const ushort4*)(xrb + doff[idx] + c);
                float m0 = acc[mt][0][r] + bf2f(gl4.x) + bf2f(gr4.x);
                float m1 = acc[mt][1][r] + bf2f(gl4.y) + bf2f(gr4.y);
                float m2 = acc[mt][2][r] + bf2f(gl4.z) + bf2f(gr4.z);
                float m3 = acc[mt][3][r] + bf2f(gl4.w) + bf2f(gr4.w);
                m0 = fmaxf(m0, NEG * m0);
                m1 = fmaxf(m1, NEG * m1);
                m2 = fmaxf(m2, NEG * m2);
                m3 = fmaxf(m3, NEG * m3);
                float p;
                p = atv.x * m0;
                p = fmaf(atv.y, m1, p);
                p = fmaf(atv.z, m2, p);
                p = fmaf(atv.w, m3, p);
                p = row_sum16(p);
                int e = e0 + mt * 16 + l4 * 4 + r;
                if (l15 == 0 && e < Ee)
                    alpha[(size_t)e * 4 + cb] = p;
            }
        }
    }
}

// ---- K4: fused per-node softmax + aggregation, atomic-free ----
// Block = node; wave = head; lane = channel. SINGLE pass with online softmax
// (running max m; rescale d/acc on new max — wave-uniform branch). Cross-head
// combine via 1KB LDS + one barrier. 4x the load streams of the R10 version,
// half the serial chain length.
__global__ __launch_bounds__(256) void node_aggr_kernel(
    const unsigned short* __restrict__ xlb,
    const int* __restrict__ csr_e, const int* __restrict__ csr_s,
    const float* __restrict__ alpha, const int* __restrict__ off,
    const int* __restrict__ deg, const float* __restrict__ bias,
    float* __restrict__ out)
{
    __shared__ float sh[4][OUTC];
    const int n    = blockIdx.x;
    const int lane = threadIdx.x & 63;
    const int h    = threadIdx.x >> 6;

    const int start = off[n];
    const int len   = deg[n];

    float m = -3.4e38f, d = 0.f, acc = 0.f;
    for (int i = 0; i < len; ++i) {
        int e = csr_e[start + i];
        int s = csr_s[start + i];
        float a  = alpha[(size_t)e * 4 + h];
        float xv = bf2f(xlb[(size_t)s * HC + h * OUTC + lane]);
        if (a > m) {                       // wave-uniform (a,m lane-invariant)
            float scale = __expf(m - a);   // first hit: exp(-inf) = 0
            d *= scale; acc *= scale; m = a;
        }
        float w = __expf(a - m);
        d += w;
        acc = fmaf(w, xv, acc);
    }
    sh[h][lane] = (len > 0) ? acc / d : 0.f;
    __syncthreads();
    if (h == 0) {
        float o = bias[lane] + 0.25f * (sh[0][lane] + sh[1][lane] + sh[2][lane] + sh[3][lane]);
        out[(size_t)n * OUTC + lane] = o;
    }
}

extern "C" void kernel_launch(void* const* d_in, const int* in_sizes, int n_in,
                              void* d_out, int out_size, void* d_ws, size_t ws_size,
                              hipStream_t stream)
{
    const float* x    = (const float*)d_in[0];
    const int*   ei   = (const int*)d_in[1];
    const float* ea   = (const float*)d_in[2];
    const float* Wl   = (const float*)d_in[3];
    const float* bl   = (const float*)d_in[4];
    const float* Wr   = (const float*)d_in[5];
    const float* br   = (const float*)d_in[6];
    const float* We   = (const float*)d_in[7];
    const float* att  = (const float*)d_in[8];
    const float* bias = (const float*)d_in[9];
    float* out = (float*)d_out;

    // workspace layout (~64 MB)
    unsigned short* xlb   = (unsigned short*)d_ws;                 // N*256 bf16
    unsigned short* xrb   = xlb + (size_t)Nn * HC;                 // N*256 bf16
    float*          alpha = (float*)(xrb + (size_t)Nn * HC);       // E*4 f32
    unsigned short* wef   = (unsigned short*)(alpha + (size_t)Ee * 4); // 8192 bf16
    unsigned short* wlf   = wef + 8192;                            // 32768 bf16
    unsigned short* wrf   = wlf + 32768;                           // 32768 bf16
    int*            deg   = (int*)(wrf + 32768);                   // N
    int*            off   = deg + Nn;                              // N
    int*            cur   = off + Nn;                              // N
    int*            bsum  = cur + Nn;                              // NB
    int*            csr_e = bsum + 256;                            // E
    int*            csr_s = csr_e + Ee;                            // E

    pack_kernel<<<36, 256, 0, stream>>>(Wl, Wr, We, wlf, wrf, wef);
    gemm_kernel<<<dim3((Nn + 63) / 64, 2), 256, 0, stream>>>(x, wlf, bl, wrf, br, xlb, xrb);
    zero_kernel<<<NB, 256, 0, stream>>>(deg);
    hist_kernel<<<(Ee + 255) / 256, 256, 0, stream>>>(ei, deg);
    scan1_kernel<<<NB, 256, 0, stream>>>(deg, off, bsum);
    scan2_kernel<<<1, 256, 0, stream>>>(bsum);
    scan3_kernel<<<NB, 256, 0, stream>>>(off, bsum, cur);
    scatter_kernel<<<(Ee + 255) / 256, 256, 0, stream>>>(ei, cur, csr_e, csr_s);
    edge_alpha_kernel<<<(Ee + 127) / 128, 256, 0, stream>>>(xlb, xrb, ei, ea, wef, att, alpha);
    node_aggr_kernel<<<Nn, 256, 0, stream>>>(xlb, csr_e, csr_s, alpha, off, deg, bias, out);
}

// Round 12
// 277.679 us; speedup vs baseline: 1.1532x; 1.1532x over previous
//
#include <hip/hip_runtime.h>
#include <cstddef>

#define Nn 50000
#define Ee 500000
#define INC 128
#define HC 256      // HEADS*OUT_C
#define OUTC 64
#define EDIM 32
#define NEG 0.2f
#define NB 196      // scan blocks = ceil(Nn/256)

typedef __attribute__((ext_vector_type(8))) short short8;   // 8 bf16 = 4 VGPR
typedef __attribute__((ext_vector_type(4))) float f32x4;

// ---- bf16 helpers (RNE) ----
__device__ __forceinline__ unsigned short f2bf(float f) {
    unsigned u = __float_as_uint(f);
    return (unsigned short)((u + 0x7FFFu + ((u >> 16) & 1u)) >> 16);
}
__device__ __forceinline__ float bf2f(unsigned short v) {
    return __uint_as_float(((unsigned)v) << 16);
}

// ---- 16-lane row sum via DPP butterfly (pure VALU, no DS pipe) ----
__device__ __forceinline__ float row_sum16(float x) {
    int i;
    i = __builtin_amdgcn_mov_dpp(__float_as_int(x), 0xB1, 0xF, 0xF, true);
    x += __int_as_float(i);
    i = __builtin_amdgcn_mov_dpp(__float_as_int(x), 0x4E, 0xF, 0xF, true);
    x += __int_as_float(i);
    i = __builtin_amdgcn_mov_dpp(__float_as_int(x), 0x141, 0xF, 0xF, true);
    x += __int_as_float(i);
    i = __builtin_amdgcn_mov_dpp(__float_as_int(x), 0x140, 0xF, 0xF, true);
    x += __int_as_float(i);
    return x;
}

// ---- K_pack: Wl/Wr (T-perm, for gemm) + We (cb-perm, for edge_alpha) ----
__global__ __launch_bounds__(256) void pack_kernel(
    const float* __restrict__ Wl, const float* __restrict__ Wr,
    const float* __restrict__ We,
    unsigned short* __restrict__ wlf, unsigned short* __restrict__ wrf,
    unsigned short* __restrict__ wef)
{
    int sid = blockIdx.x * 256 + threadIdx.x;
    const float* W; unsigned short* dst; int s; int col; int k0;
    if (sid < 8192) {
        if (sid < 4096) { W = Wl; dst = wlf; s = sid; }
        else            { W = Wr; dst = wrf; s = sid - 4096; }
        int lane = s & 63;
        int T    = (s >> 6) & 15;
        int kc   = s >> 10;
        col = (lane & 15) * 16 + T;
        k0  = kc * 32 + (lane >> 4) * 8;
    } else if (sid < 9216) {
        W = We; dst = wef; s = sid - 8192;
        int lane = s & 63;
        int nt   = (s >> 6) & 3;
        int cb   = s >> 8;
        col = cb * 64 + (lane & 15) * 4 + nt;
        k0  = (lane >> 4) * 8;
    } else return;
    unsigned short tmp[8];
    #pragma unroll
    for (int j = 0; j < 8; ++j) tmp[j] = f2bf(W[(size_t)(k0 + j) * HC + col]);
    *(uint4*)(dst + (size_t)s * 8) = *(uint4*)tmp;
}

// ---- K1: Y = bf16(X @ W + b) via MFMA, no LDS ----
__global__ __launch_bounds__(256) void gemm_kernel(
    const float* __restrict__ X,
    const unsigned short* __restrict__ wlf, const float* __restrict__ bl,
    const unsigned short* __restrict__ wrf, const float* __restrict__ br,
    unsigned short* __restrict__ Ylb, unsigned short* __restrict__ Yrb)
{
    const unsigned short* wf; const float* b; unsigned short* Yb;
    if (blockIdx.y == 0) { wf = wlf; b = bl; Yb = Ylb; } else { wf = wrf; b = br; Yb = Yrb; }

    const int tid = threadIdx.x, lane = tid & 63;
    const int l15 = lane & 15, l4 = lane >> 4;
    const int r0 = blockIdx.x * 64 + (tid >> 6) * 16;

    int arow = r0 + l15; if (arow >= Nn) arow = Nn - 1;
    short8 af[4];
    #pragma unroll
    for (int kc = 0; kc < 4; ++kc) {
        const f32x4* p = (const f32x4*)(X + (size_t)arow * INC + kc * 32 + l4 * 8);
        f32x4 v0 = p[0], v1 = p[1];
        short8 a;
        a[0]=(short)f2bf(v0.x); a[1]=(short)f2bf(v0.y); a[2]=(short)f2bf(v0.z); a[3]=(short)f2bf(v0.w);
        a[4]=(short)f2bf(v1.x); a[5]=(short)f2bf(v1.y); a[6]=(short)f2bf(v1.z); a[7]=(short)f2bf(v1.w);
        af[kc] = a;
    }

    f32x4 acc[16];
    #pragma unroll
    for (int T = 0; T < 16; ++T) acc[T] = (f32x4){0.f, 0.f, 0.f, 0.f};

    #pragma unroll
    for (int kc = 0; kc < 4; ++kc) {
        #pragma unroll
        for (int T = 0; T < 16; ++T) {
            short8 bf = *(const short8*)(wf + ((size_t)(kc * 16 + T) * 64 + lane) * 8);
            acc[T] = __builtin_amdgcn_mfma_f32_16x16x32_bf16(af[kc], bf, acc[T], 0, 0, 0);
        }
    }

    float bb[16];
    #pragma unroll
    for (int t4 = 0; t4 < 4; ++t4) {
        float4 v = *(const float4*)(b + l15 * 16 + t4 * 4);
        bb[t4*4+0]=v.x; bb[t4*4+1]=v.y; bb[t4*4+2]=v.z; bb[t4*4+3]=v.w;
    }

    #pragma unroll
    for (int r = 0; r < 4; ++r) {
        int orow = r0 + l4 * 4 + r;
        if (orow < Nn) {
            unsigned short o[16];
            #pragma unroll
            for (int T = 0; T < 16; ++T) o[T] = f2bf(acc[T][r] + bb[T]);
            *(uint4*)(Yb + (size_t)orow * HC + l15 * 16)     = *(uint4*)(o);
            *(uint4*)(Yb + (size_t)orow * HC + l15 * 16 + 8) = *(uint4*)(o + 8);
        }
    }
}

// ---- CSR build ----
__global__ __launch_bounds__(256) void zero_kernel(int* __restrict__ deg) {
    int i = blockIdx.x * 256 + threadIdx.x;
    if (i < Nn) deg[i] = 0;
}
__global__ __launch_bounds__(256) void hist_kernel(
    const int* __restrict__ ei, int* __restrict__ deg) {
    int e = blockIdx.x * 256 + threadIdx.x;
    if (e < Ee) atomicAdd(deg + ei[Ee + e], 1);
}
__global__ __launch_bounds__(256) void scan1_kernel(
    const int* __restrict__ deg, int* __restrict__ off, int* __restrict__ bsum) {
    __shared__ int s[256];
    int i = blockIdx.x * 256 + threadIdx.x;
    int v = (i < Nn) ? deg[i] : 0;
    s[threadIdx.x] = v;
    __syncthreads();
    #pragma unroll
    for (int d = 1; d < 256; d <<= 1) {
        int t = (threadIdx.x >= d) ? s[threadIdx.x - d] : 0;
        __syncthreads();
        s[threadIdx.x] += t;
        __syncthreads();
    }
    if (i < Nn) off[i] = s[threadIdx.x] - v;
    if (threadIdx.x == 255) bsum[blockIdx.x] = s[255];
}
__global__ __launch_bounds__(256) void scan2_kernel(int* __restrict__ bsum) {
    __shared__ int s[256];
    int v = (threadIdx.x < NB) ? bsum[threadIdx.x] : 0;
    s[threadIdx.x] = v;
    __syncthreads();
    #pragma unroll
    for (int d = 1; d < 256; d <<= 1) {
        int t = (threadIdx.x >= d) ? s[threadIdx.x - d] : 0;
        __syncthreads();
        s[threadIdx.x] += t;
        __syncthreads();
    }
    if (threadIdx.x < NB) bsum[threadIdx.x] = s[threadIdx.x] - v;
}
__global__ __launch_bounds__(256) void scan3_kernel(
    int* __restrict__ off, const int* __restrict__ bsum, int* __restrict__ cur) {
    int i = blockIdx.x * 256 + threadIdx.x;
    if (i < Nn) {
        int o = off[i] + bsum[blockIdx.x];
        off[i] = o;
        cur[i] = o;
    }
}
__global__ __launch_bounds__(256) void scatter_kernel(
    const int* __restrict__ ei, int* __restrict__ cur,
    int* __restrict__ csr_e, int* __restrict__ csr_s) {
    int e = blockIdx.x * 256 + threadIdx.x;
    if (e >= Ee) return;
    int d = ei[Ee + e];
    int pos = atomicAdd(cur + d, 1);
    csr_e[pos] = e;
    csr_s[pos] = ei[e];
}

// ---- K2: per-edge logits via MFMA bf16, no LDS, DPP reduce, NO atomics ----
__global__ __launch_bounds__(256) void edge_alpha_kernel(
    const unsigned short* __restrict__ xlb, const unsigned short* __restrict__ xrb,
    const int* __restrict__ ei, const float* __restrict__ ea,
    const unsigned short* __restrict__ wef, const float* __restrict__ att,
    float* __restrict__ alpha)
{
    const int tid  = threadIdx.x;
    const int lane = tid & 63;
    const int l15  = lane & 15, l4 = lane >> 4;
    const int e0   = blockIdx.x * 128 + (tid >> 6) * 32;

    short8 afrag[2];
    #pragma unroll
    for (int mt = 0; mt < 2; ++mt) {
        int e = e0 + mt * 16 + l15;
        if (e >= Ee) e = Ee - 1;
        const f32x4* p = (const f32x4*)(ea + (size_t)e * EDIM + l4 * 8);
        f32x4 v0 = __builtin_nontemporal_load(p);
        f32x4 v1 = __builtin_nontemporal_load(p + 1);
        short8 a;
        a[0]=(short)f2bf(v0.x); a[1]=(short)f2bf(v0.y); a[2]=(short)f2bf(v0.z); a[3]=(short)f2bf(v0.w);
        a[4]=(short)f2bf(v1.x); a[5]=(short)f2bf(v1.y); a[6]=(short)f2bf(v1.z); a[7]=(short)f2bf(v1.w);
        afrag[mt] = a;
    }

    unsigned soff[8], doff[8];
    #pragma unroll
    for (int mt = 0; mt < 2; ++mt)
        #pragma unroll
        for (int r = 0; r < 4; ++r) {
            int idx = mt * 4 + r;
            int e = e0 + mt * 16 + l4 * 4 + r;
            int ec = (e < Ee) ? e : Ee - 1;
            soff[idx] = (unsigned)ei[ec] * (unsigned)HC;
            doff[idx] = (unsigned)ei[Ee + ec] * (unsigned)HC;
        }

    #pragma unroll 1
    for (int cb = 0; cb < 4; ++cb) {
        short8 bfrag[4];
        #pragma unroll
        for (int nt = 0; nt < 4; ++nt)
            bfrag[nt] = *(const short8*)(wef + ((size_t)(cb * 4 + nt) * 64 + lane) * 8);

        f32x4 acc[2][4];
        const f32x4 z = {0.f, 0.f, 0.f, 0.f};
        #pragma unroll
        for (int mt = 0; mt < 2; ++mt)
            #pragma unroll
            for (int nt = 0; nt < 4; ++nt)
                acc[mt][nt] = __builtin_amdgcn_mfma_f32_16x16x32_bf16(
                    afrag[mt], bfrag[nt], z, 0, 0, 0);

        float4 atv = *(const float4*)(att + cb * 64 + l15 * 4);

        #pragma unroll
        for (int mt = 0; mt < 2; ++mt) {
            #pragma unroll
            for (int r = 0; r < 4; ++r) {
                const int idx = mt * 4 + r;
                const unsigned c = (unsigned)(cb * 64 + l15 * 4);
                ushort4 gl4 = *(const ushort4*)(xlb + soff[idx] + c);
                ushort4 gr4 = *(const ushort4*)(xrb + doff[idx] + c);
                float m0 = acc[mt][0][r] + bf2f(gl4.x) + bf2f(gr4.x);
                float m1 = acc[mt][1][r] + bf2f(gl4.y) + bf2f(gr4.y);
                float m2 = acc[mt][2][r] + bf2f(gl4.z) + bf2f(gr4.z);
                float m3 = acc[mt][3][r] + bf2f(gl4.w) + bf2f(gr4.w);
                m0 = fmaxf(m0, NEG * m0);
                m1 = fmaxf(m1, NEG * m1);
                m2 = fmaxf(m2, NEG * m2);
                m3 = fmaxf(m3, NEG * m3);
                float p;
                p = atv.x * m0;
                p = fmaf(atv.y, m1, p);
                p = fmaf(atv.z, m2, p);
                p = fmaf(atv.w, m3, p);
                p = row_sum16(p);
                int e = e0 + mt * 16 + l4 * 4 + r;
                if (l15 == 0 && e < Ee)
                    alpha[(size_t)e * 4 + cb] = p;
            }
        }
    }
}

// ---- K4: fused per-node softmax + aggregation, atomic-free ----
// Block = node; wave = head; lane dual-role. Per <=64-edge chunk:
//   stage (lane=edge): coalesced csr/alpha loads, wave max (6 shfl), one exp,
//   wave sum (6 shfl), park {w, src} in LDS.
//   aggregate (lane=channel): tight loop {uniform LDS read, coalesced 128B
//   gather, fma} — loads independent, unroll-4 pipelined.
// Chunked online rescale (wave-uniform scalars) handles deg > 64 exactly.
__global__ __launch_bounds__(256) void node_aggr_kernel(
    const unsigned short* __restrict__ xlb,
    const int* __restrict__ csr_e, const int* __restrict__ csr_s,
    const float* __restrict__ alpha, const int* __restrict__ off,
    const int* __restrict__ deg, const float* __restrict__ bias,
    float* __restrict__ out)
{
    __shared__ float sh[4][OUTC];
    __shared__ float shw[4][64];
    __shared__ int   shs[4][64];
    const int n    = blockIdx.x;
    const int lane = threadIdx.x & 63;
    const int h    = threadIdx.x >> 6;

    const int start = off[n];
    const int len   = deg[n];

    float m = -3.4e38f, d = 0.f, acc = 0.f;
    for (int c0 = 0; c0 < len; c0 += 64) {
        int cl = len - c0; if (cl > 64) cl = 64;
        float a = -3.4e38f;
        int   s = 0;
        if (lane < cl) {
            int e = csr_e[start + c0 + lane];
            s = csr_s[start + c0 + lane];
            a = alpha[(size_t)e * 4 + h];
        }
        // wave-wide max (result uniform)
        float cm = a;
        #pragma unroll
        for (int k = 1; k < 64; k <<= 1)
            cm = fmaxf(cm, __shfl_xor(cm, k, 64));
        if (cm > m) {                       // wave-uniform
            float sc = __expf(m - cm);      // first chunk: exp(-inf)=0
            d *= sc; acc *= sc; m = cm;
        }
        float w = (lane < cl) ? __expf(a - m) : 0.f;
        float ws = w;
        #pragma unroll
        for (int k = 1; k < 64; k <<= 1)
            ws += __shfl_xor(ws, k, 64);
        d += ws;
        shw[h][lane] = w;
        shs[h][lane] = s;
        // same-wave LDS write->read (lgkmcnt ordering, no barrier needed)
        #pragma unroll 4
        for (int i = 0; i < cl; ++i) {
            float wi = shw[h][i];
            int   si = shs[h][i];
            acc = fmaf(wi, bf2f(xlb[(size_t)si * HC + h * OUTC + lane]), acc);
        }
    }
    sh[h][lane] = (len > 0) ? acc / d : 0.f;
    __syncthreads();
    if (h == 0) {
        float o = bias[lane] + 0.25f * (sh[0][lane] + sh[1][lane] + sh[2][lane] + sh[3][lane]);
        out[(size_t)n * OUTC + lane] = o;
    }
}

extern "C" void kernel_launch(void* const* d_in, const int* in_sizes, int n_in,
                              void* d_out, int out_size, void* d_ws, size_t ws_size,
                              hipStream_t stream)
{
    const float* x    = (const float*)d_in[0];
    const int*   ei   = (const int*)d_in[1];
    const float* ea   = (const float*)d_in[2];
    const float* Wl   = (const float*)d_in[3];
    const float* bl   = (const float*)d_in[4];
    const float* Wr   = (const float*)d_in[5];
    const float* br   = (const float*)d_in[6];
    const float* We   = (const float*)d_in[7];
    const float* att  = (const float*)d_in[8];
    const float* bias = (const float*)d_in[9];
    float* out = (float*)d_out;

    // workspace layout (~64 MB)
    unsigned short* xlb   = (unsigned short*)d_ws;                 // N*256 bf16
    unsigned short* xrb   = xlb + (size_t)Nn * HC;                 // N*256 bf16
    float*          alpha = (float*)(xrb + (size_t)Nn * HC);       // E*4 f32
    unsigned short* wef   = (unsigned short*)(alpha + (size_t)Ee * 4); // 8192 bf16
    unsigned short* wlf   = wef + 8192;                            // 32768 bf16
    unsigned short* wrf   = wlf + 32768;                           // 32768 bf16
    int*            deg   = (int*)(wrf + 32768);                   // N
    int*            off   = deg + Nn;                              // N
    int*            cur   = off + Nn;                              // N
    int*            bsum  = cur + Nn;                              // NB
    int*            csr_e = bsum + 256;                            // E
    int*            csr_s = csr_e + Ee;                            // E

    pack_kernel<<<36, 256, 0, stream>>>(Wl, Wr, We, wlf, wrf, wef);
    gemm_kernel<<<dim3((Nn + 63) / 64, 2), 256, 0, stream>>>(x, wlf, bl, wrf, br, xlb, xrb);
    zero_kernel<<<NB, 256, 0, stream>>>(deg);
    hist_kernel<<<(Ee + 255) / 256, 256, 0, stream>>>(ei, deg);
    scan1_kernel<<<NB, 256, 0, stream>>>(deg, off, bsum);
    scan2_kernel<<<1, 256, 0, stream>>>(bsum);
    scan3_kernel<<<NB, 256, 0, stream>>>(off, bsum, cur);
    scatter_kernel<<<(Ee + 255) / 256, 256, 0, stream>>>(ei, cur, csr_e, csr_s);
    edge_alpha_kernel<<<(Ee + 127) / 128, 256, 0, stream>>>(xlb, xrb, ei, ea, wef, att, alpha);
    node_aggr_kernel<<<Nn, 256, 0, stream>>>(xlb, csr_e, csr_s, alpha, off, deg, bias, out);
}

// Round 13
// 233.586 us; speedup vs baseline: 1.3709x; 1.1888x over previous
//
#include <hip/hip_runtime.h>
#include <cstddef>

#define Nn 50000
#define Ee 500000
#define INC 128
#define HC 256      // HEADS*OUT_C
#define OUTC 64
#define EDIM 32
#define NEG 0.2f
#define NB 196      // scan blocks = ceil(Nn/256)

typedef __attribute__((ext_vector_type(8))) short short8;   // 8 bf16 = 4 VGPR
typedef __attribute__((ext_vector_type(4))) float f32x4;

// ---- bf16 helpers (RNE) ----
__device__ __forceinline__ unsigned short f2bf(float f) {
    unsigned u = __float_as_uint(f);
    return (unsigned short)((u + 0x7FFFu + ((u >> 16) & 1u)) >> 16);
}
__device__ __forceinline__ float bf2f(unsigned short v) {
    return __uint_as_float(((unsigned)v) << 16);
}

// ---- 16-lane row sum via DPP butterfly (pure VALU, no DS pipe) ----
__device__ __forceinline__ float row_sum16(float x) {
    int i;
    i = __builtin_amdgcn_mov_dpp(__float_as_int(x), 0xB1, 0xF, 0xF, true);
    x += __int_as_float(i);
    i = __builtin_amdgcn_mov_dpp(__float_as_int(x), 0x4E, 0xF, 0xF, true);
    x += __int_as_float(i);
    i = __builtin_amdgcn_mov_dpp(__float_as_int(x), 0x141, 0xF, 0xF, true);
    x += __int_as_float(i);
    i = __builtin_amdgcn_mov_dpp(__float_as_int(x), 0x140, 0xF, 0xF, true);
    x += __int_as_float(i);
    return x;
}

// ---- K_pack: Wl/Wr (T-perm, for gemm) + We (cb-perm, for edge_alpha) ----
__global__ __launch_bounds__(256) void pack_kernel(
    const float* __restrict__ Wl, const float* __restrict__ Wr,
    const float* __restrict__ We,
    unsigned short* __restrict__ wlf, unsigned short* __restrict__ wrf,
    unsigned short* __restrict__ wef)
{
    int sid = blockIdx.x * 256 + threadIdx.x;
    const float* W; unsigned short* dst; int s; int col; int k0;
    if (sid < 8192) {
        if (sid < 4096) { W = Wl; dst = wlf; s = sid; }
        else            { W = Wr; dst = wrf; s = sid - 4096; }
        int lane = s & 63;
        int T    = (s >> 6) & 15;
        int kc   = s >> 10;
        col = (lane & 15) * 16 + T;
        k0  = kc * 32 + (lane >> 4) * 8;
    } else if (sid < 9216) {
        W = We; dst = wef; s = sid - 8192;
        int lane = s & 63;
        int nt   = (s >> 6) & 3;
        int cb   = s >> 8;
        col = cb * 64 + (lane & 15) * 4 + nt;
        k0  = (lane >> 4) * 8;
    } else return;
    unsigned short tmp[8];
    #pragma unroll
    for (int j = 0; j < 8; ++j) tmp[j] = f2bf(W[(size_t)(k0 + j) * HC + col]);
    *(uint4*)(dst + (size_t)s * 8) = *(uint4*)tmp;
}

// ---- K1: Y = bf16(X @ W + b) via MFMA, no LDS ----
__global__ __launch_bounds__(256) void gemm_kernel(
    const float* __restrict__ X,
    const unsigned short* __restrict__ wlf, const float* __restrict__ bl,
    const unsigned short* __restrict__ wrf, const float* __restrict__ br,
    unsigned short* __restrict__ Ylb, unsigned short* __restrict__ Yrb)
{
    const unsigned short* wf; const float* b; unsigned short* Yb;
    if (blockIdx.y == 0) { wf = wlf; b = bl; Yb = Ylb; } else { wf = wrf; b = br; Yb = Yrb; }

    const int tid = threadIdx.x, lane = tid & 63;
    const int l15 = lane & 15, l4 = lane >> 4;
    const int r0 = blockIdx.x * 64 + (tid >> 6) * 16;

    int arow = r0 + l15; if (arow >= Nn) arow = Nn - 1;
    short8 af[4];
    #pragma unroll
    for (int kc = 0; kc < 4; ++kc) {
        const f32x4* p = (const f32x4*)(X + (size_t)arow * INC + kc * 32 + l4 * 8);
        f32x4 v0 = p[0], v1 = p[1];
        short8 a;
        a[0]=(short)f2bf(v0.x); a[1]=(short)f2bf(v0.y); a[2]=(short)f2bf(v0.z); a[3]=(short)f2bf(v0.w);
        a[4]=(short)f2bf(v1.x); a[5]=(short)f2bf(v1.y); a[6]=(short)f2bf(v1.z); a[7]=(short)f2bf(v1.w);
        af[kc] = a;
    }

    f32x4 acc[16];
    #pragma unroll
    for (int T = 0; T < 16; ++T) acc[T] = (f32x4){0.f, 0.f, 0.f, 0.f};

    #pragma unroll
    for (int kc = 0; kc < 4; ++kc) {
        #pragma unroll
        for (int T = 0; T < 16; ++T) {
            short8 bf = *(const short8*)(wf + ((size_t)(kc * 16 + T) * 64 + lane) * 8);
            acc[T] = __builtin_amdgcn_mfma_f32_16x16x32_bf16(af[kc], bf, acc[T], 0, 0, 0);
        }
    }

    float bb[16];
    #pragma unroll
    for (int t4 = 0; t4 < 4; ++t4) {
        float4 v = *(const float4*)(b + l15 * 16 + t4 * 4);
        bb[t4*4+0]=v.x; bb[t4*4+1]=v.y; bb[t4*4+2]=v.z; bb[t4*4+3]=v.w;
    }

    #pragma unroll
    for (int r = 0; r < 4; ++r) {
        int orow = r0 + l4 * 4 + r;
        if (orow < Nn) {
            unsigned short o[16];
            #pragma unroll
            for (int T = 0; T < 16; ++T) o[T] = f2bf(acc[T][r] + bb[T]);
            *(uint4*)(Yb + (size_t)orow * HC + l15 * 16)     = *(uint4*)(o);
            *(uint4*)(Yb + (size_t)orow * HC + l15 * 16 + 8) = *(uint4*)(o + 8);
        }
    }
}

// ---- CSR build ----
__global__ __launch_bounds__(256) void zero_kernel(int* __restrict__ deg) {
    int i = blockIdx.x * 256 + threadIdx.x;
    if (i < Nn) deg[i] = 0;
}
__global__ __launch_bounds__(256) void hist_kernel(
    const int* __restrict__ ei, int* __restrict__ deg) {
    int e = blockIdx.x * 256 + threadIdx.x;
    if (e < Ee) atomicAdd(deg + ei[Ee + e], 1);
}
__global__ __launch_bounds__(256) void scan1_kernel(
    const int* __restrict__ deg, int* __restrict__ off, int* __restrict__ bsum) {
    __shared__ int s[256];
    int i = blockIdx.x * 256 + threadIdx.x;
    int v = (i < Nn) ? deg[i] : 0;
    s[threadIdx.x] = v;
    __syncthreads();
    #pragma unroll
    for (int d = 1; d < 256; d <<= 1) {
        int t = (threadIdx.x >= d) ? s[threadIdx.x - d] : 0;
        __syncthreads();
        s[threadIdx.x] += t;
        __syncthreads();
    }
    if (i < Nn) off[i] = s[threadIdx.x] - v;
    if (threadIdx.x == 255) bsum[blockIdx.x] = s[255];
}
__global__ __launch_bounds__(256) void scan2_kernel(int* __restrict__ bsum) {
    __shared__ int s[256];
    int v = (threadIdx.x < NB) ? bsum[threadIdx.x] : 0;
    s[threadIdx.x] = v;
    __syncthreads();
    #pragma unroll
    for (int d = 1; d < 256; d <<= 1) {
        int t = (threadIdx.x >= d) ? s[threadIdx.x - d] : 0;
        __syncthreads();
        s[threadIdx.x] += t;
        __syncthreads();
    }
    if (threadIdx.x < NB) bsum[threadIdx.x] = s[threadIdx.x] - v;
}
__global__ __launch_bounds__(256) void scan3_kernel(
    int* __restrict__ off, const int* __restrict__ bsum, int* __restrict__ cur) {
    int i = blockIdx.x * 256 + threadIdx.x;
    if (i < Nn) {
        int o = off[i] + bsum[blockIdx.x];
        off[i] = o;
        cur[i] = o;
    }
}
__global__ __launch_bounds__(256) void scatter_kernel(
    const int* __restrict__ ei, int* __restrict__ cur,
    int* __restrict__ csr_e, int* __restrict__ csr_s) {
    int e = blockIdx.x * 256 + threadIdx.x;
    if (e >= Ee) return;
    int d = ei[Ee + e];
    int pos = atomicAdd(cur + d, 1);
    csr_e[pos] = e;
    csr_s[pos] = ei[e];
}

// ---- K2: per-edge logits via MFMA bf16, no LDS, DPP reduce, NO atomics ----
__global__ __launch_bounds__(256) void edge_alpha_kernel(
    const unsigned short* __restrict__ xlb, const unsigned short* __restrict__ xrb,
    const int* __restrict__ ei, const float* __restrict__ ea,
    const unsigned short* __restrict__ wef, const float* __restrict__ att,
    float* __restrict__ alpha)
{
    const int tid  = threadIdx.x;
    const int lane = tid & 63;
    const int l15  = lane & 15, l4 = lane >> 4;
    const int e0   = blockIdx.x * 128 + (tid >> 6) * 32;

    short8 afrag[2];
    #pragma unroll
    for (int mt = 0; mt < 2; ++mt) {
        int e = e0 + mt * 16 + l15;
        if (e >= Ee) e = Ee - 1;
        const f32x4* p = (const f32x4*)(ea + (size_t)e * EDIM + l4 * 8);
        f32x4 v0 = __builtin_nontemporal_load(p);
        f32x4 v1 = __builtin_nontemporal_load(p + 1);
        short8 a;
        a[0]=(short)f2bf(v0.x); a[1]=(short)f2bf(v0.y); a[2]=(short)f2bf(v0.z); a[3]=(short)f2bf(v0.w);
        a[4]=(short)f2bf(v1.x); a[5]=(short)f2bf(v1.y); a[6]=(short)f2bf(v1.z); a[7]=(short)f2bf(v1.w);
        afrag[mt] = a;
    }

    unsigned soff[8], doff[8];
    #pragma unroll
    for (int mt = 0; mt < 2; ++mt)
        #pragma unroll
        for (int r = 0; r < 4; ++r) {
            int idx = mt * 4 + r;
            int e = e0 + mt * 16 + l4 * 4 + r;
            int ec = (e < Ee) ? e : Ee - 1;
            soff[idx] = (unsigned)ei[ec] * (unsigned)HC;
            doff[idx] = (unsigned)ei[Ee + ec] * (unsigned)HC;
        }

    #pragma unroll 1
    for (int cb = 0; cb < 4; ++cb) {
        short8 bfrag[4];
        #pragma unroll
        for (int nt = 0; nt < 4; ++nt)
            bfrag[nt] = *(const short8*)(wef + ((size_t)(cb * 4 + nt) * 64 + lane) * 8);

        f32x4 acc[2][4];
        const f32x4 z = {0.f, 0.f, 0.f, 0.f};
        #pragma unroll
        for (int mt = 0; mt < 2; ++mt)
            #pragma unroll
            for (int nt = 0; nt < 4; ++nt)
                acc[mt][nt] = __builtin_amdgcn_mfma_f32_16x16x32_bf16(
                    afrag[mt], bfrag[nt], z, 0, 0, 0);

        float4 atv = *(const float4*)(att + cb * 64 + l15 * 4);

        #pragma unroll
        for (int mt = 0; mt < 2; ++mt) {
            #pragma unroll
            for (int r = 0; r < 4; ++r) {
                const int idx = mt * 4 + r;
                const unsigned c = (unsigned)(cb * 64 + l15 * 4);
                ushort4 gl4 = *(const ushort4*)(xlb + soff[idx] + c);
                ushort4 gr4 = *(const ushort4*)(xrb + doff[idx] + c);
                float m0 = acc[mt][0][r] + bf2f(gl4.x) + bf2f(gr4.x);
                float m1 = acc[mt][1][r] + bf2f(gl4.y) + bf2f(gr4.y);
                float m2 = acc[mt][2][r] + bf2f(gl4.z) + bf2f(gr4.z);
                float m3 = acc[mt][3][r] + bf2f(gl4.w) + bf2f(gr4.w);
                m0 = fmaxf(m0, NEG * m0);
                m1 = fmaxf(m1, NEG * m1);
                m2 = fmaxf(m2, NEG * m2);
                m3 = fmaxf(m3, NEG * m3);
                float p;
                p = atv.x * m0;
                p = fmaf(atv.y, m1, p);
                p = fmaf(atv.z, m2, p);
                p = fmaf(atv.w, m3, p);
                p = row_sum16(p);
                int e = e0 + mt * 16 + l4 * 4 + r;
                if (l15 == 0 && e < Ee)
                    alpha[(size_t)e * 4 + cb] = p;
            }
        }
    }
}

// ---- K4: fused per-node softmax + aggregation, ONE WAVE PER NODE ----
// 4 independent waves per block (no barrier). Per <=16-edge chunk:
//   stage (lane = edge*4+head): coalesced alpha float loads, per-head max/sum
//   via 4x shfl_xor stride-4 class reduce, one exp/lane, park {w,src} in LDS.
//   aggregate (lane = channel-quad): ONE 512B coalesced row gather per edge
//   (ushort4/lane), 4 fma; unroll-4 pipelines gathers.
// Branchless online rescale handles deg>16. Epilogue: /d_h (shfl'd), stride-16
// shfl reduce across heads, lanes 0-15 store 256B coalesced.
__global__ __launch_bounds__(256) void node_aggr_kernel(
    const unsigned short* __restrict__ xlb,
    const int* __restrict__ csr_e, const int* __restrict__ csr_s,
    const float* __restrict__ alpha, const int* __restrict__ off,
    const int* __restrict__ deg, const float* __restrict__ bias,
    float* __restrict__ out)
{
    __shared__ float shw[4][64];
    __shared__ int   shs[4][16];
    const int lane = threadIdx.x & 63;
    const int wv   = threadIdx.x >> 6;
    const int n    = blockIdx.x * 4 + wv;
    if (n >= Nn) return;

    const int start = off[n];
    const int len   = deg[n];

    if (len == 0) {
        if (lane < 16) {
            float4 b4 = *(const float4*)(bias + lane * 4);
            *(float4*)(out + (size_t)n * OUTC + lane * 4) = b4;
        }
        return;
    }

    const int eidx = lane >> 2;     // staging: edge slot 0..15
    const int hh   = lane & 3;      // staging: head
    const int hagg = lane >> 4;     // aggregation: head of this lane's quad

    float m = -3.4e38f, d = 0.f;
    float4 acc = make_float4(0.f, 0.f, 0.f, 0.f);

    for (int c0 = 0; c0 < len; c0 += 16) {
        int cl = len - c0; if (cl > 16) cl = 16;
        float a = -3.4e38f;
        if (eidx < cl) {
            int e = csr_e[start + c0 + eidx];
            a = alpha[(size_t)e * 4 + hh];
        }
        if (lane < cl) shs[wv][lane] = csr_s[start + c0 + lane];
        // per-head chunk max (stride-4 class reduce, result uniform per class)
        float cm = a;
        cm = fmaxf(cm, __shfl_xor(cm, 4, 64));
        cm = fmaxf(cm, __shfl_xor(cm, 8, 64));
        cm = fmaxf(cm, __shfl_xor(cm, 16, 64));
        cm = fmaxf(cm, __shfl_xor(cm, 32, 64));
        float mn = fmaxf(m, cm);
        float sc = __expf(m - mn);          // 1 if unchanged; 0 on first chunk
        float w  = (eidx < cl) ? __expf(a - mn) : 0.f;
        float ws = w;
        ws += __shfl_xor(ws, 4, 64);
        ws += __shfl_xor(ws, 8, 64);
        ws += __shfl_xor(ws, 16, 64);
        ws += __shfl_xor(ws, 32, 64);
        d = d * sc + ws;
        m = mn;
        shw[wv][lane] = w;                  // slot = edge*4 + head
        // rescale acc by this lane's aggregation-head scale (lane h holds class h)
        float sca = __shfl(sc, hagg, 64);
        acc.x *= sca; acc.y *= sca; acc.z *= sca; acc.w *= sca;
        #pragma unroll 4
        for (int i = 0; i < cl; ++i) {
            int   si = shs[wv][i];
            float wi = shw[wv][i * 4 + hagg];
            ushort4 g = *(const ushort4*)(xlb + (size_t)si * HC + lane * 4);
            acc.x = fmaf(wi, bf2f(g.x), acc.x);
            acc.y = fmaf(wi, bf2f(g.y), acc.y);
            acc.z = fmaf(wi, bf2f(g.z), acc.z);
            acc.w = fmaf(wi, bf2f(g.w), acc.w);
        }
    }

    float dh = __shfl(d, hagg, 64);
    float di = 1.f / dh;
    float4 r;
    r.x = acc.x * di; r.y = acc.y * di; r.z = acc.z * di; r.w = acc.w * di;
    // reduce across heads (lanes stride 16)
    r.x += __shfl_xor(r.x, 16, 64); r.y += __shfl_xor(r.y, 16, 64);
    r.z += __shfl_xor(r.z, 16, 64); r.w += __shfl_xor(r.w, 16, 64);
    r.x += __shfl_xor(r.x, 32, 64); r.y += __shfl_xor(r.y, 32, 64);
    r.z += __shfl_xor(r.z, 32, 64); r.w += __shfl_xor(r.w, 32, 64);
    if (lane < 16) {
        float4 b4 = *(const float4*)(bias + lane * 4);
        float4 o = make_float4(b4.x + 0.25f * r.x, b4.y + 0.25f * r.y,
                               b4.z + 0.25f * r.z, b4.w + 0.25f * r.w);
        *(float4*)(out + (size_t)n * OUTC + lane * 4) = o;
    }
}

extern "C" void kernel_launch(void* const* d_in, const int* in_sizes, int n_in,
                              void* d_out, int out_size, void* d_ws, size_t ws_size,
                              hipStream_t stream)
{
    const float* x    = (const float*)d_in[0];
    const int*   ei   = (const int*)d_in[1];
    const float* ea   = (const float*)d_in[2];
    const float* Wl   = (const float*)d_in[3];
    const float* bl   = (const float*)d_in[4];
    const float* Wr   = (const float*)d_in[5];
    const float* br   = (const float*)d_in[6];
    const float* We   = (const float*)d_in[7];
    const float* att  = (const float*)d_in[8];
    const float* bias = (const float*)d_in[9];
    float* out = (float*)d_out;

    // workspace layout (~64 MB)
    unsigned short* xlb   = (unsigned short*)d_ws;                 // N*256 bf16
    unsigned short* xrb   = xlb + (size_t)Nn * HC;                 // N*256 bf16
    float*          alpha = (float*)(xrb + (size_t)Nn * HC);       // E*4 f32
    unsigned short* wef   = (unsigned short*)(alpha + (size_t)Ee * 4); // 8192 bf16
    unsigned short* wlf   = wef + 8192;                            // 32768 bf16
    unsigned short* wrf   = wlf + 32768;                           // 32768 bf16
    int*            deg   = (int*)(wrf + 32768);                   // N
    int*            off   = deg + Nn;                              // N
    int*            cur   = off + Nn;                              // N
    int*            bsum  = cur + Nn;                              // NB
    int*            csr_e = bsum + 256;                            // E
    int*            csr_s = csr_e + Ee;                            // E

    pack_kernel<<<36, 256, 0, stream>>>(Wl, Wr, We, wlf, wrf, wef);
    gemm_kernel<<<dim3((Nn + 63) / 64, 2), 256, 0, stream>>>(x, wlf, bl, wrf, br, xlb, xrb);
    zero_kernel<<<NB, 256, 0, stream>>>(deg);
    hist_kernel<<<(Ee + 255) / 256, 256, 0, stream>>>(ei, deg);
    scan1_kernel<<<NB, 256, 0, stream>>>(deg, off, bsum);
    scan2_kernel<<<1, 256, 0, stream>>>(bsum);
    scan3_kernel<<<NB, 256, 0, stream>>>(off, bsum, cur);
    scatter_kernel<<<(Ee + 255) / 256, 256, 0, stream>>>(ei, cur, csr_e, csr_s);
    edge_alpha_kernel<<<(Ee + 127) / 128, 256, 0, stream>>>(xlb, xrb, ei, ea, wef, att, alpha);
    node_aggr_kernel<<<(Nn + 3) / 4, 256, 0, stream>>>(xlb, csr_e, csr_s, alpha, off, deg, bias, out);
}

// Round 14
// 228.568 us; speedup vs baseline: 1.4010x; 1.0220x over previous
//
#include <hip/hip_runtime.h>
#include <cstddef>

#define Nn 50000
#define Ee 500000
#define INC 128
#define HC 256      // HEADS*OUT_C
#define OUTC 64
#define EDIM 32
#define NEG 0.2f
#define NB 196      // scan blocks = ceil(Nn/256)

typedef __attribute__((ext_vector_type(8))) short short8;   // 8 bf16 = 4 VGPR
typedef __attribute__((ext_vector_type(4))) float f32x4;

// ---- bf16 helpers (RNE) ----
__device__ __forceinline__ unsigned short f2bf(float f) {
    unsigned u = __float_as_uint(f);
    return (unsigned short)((u + 0x7FFFu + ((u >> 16) & 1u)) >> 16);
}
__device__ __forceinline__ float bf2f(unsigned short v) {
    return __uint_as_float(((unsigned)v) << 16);
}

// ---- 16-lane row sum via DPP butterfly (pure VALU, no DS pipe) ----
__device__ __forceinline__ float row_sum16(float x) {
    int i;
    i = __builtin_amdgcn_mov_dpp(__float_as_int(x), 0xB1, 0xF, 0xF, true);
    x += __int_as_float(i);
    i = __builtin_amdgcn_mov_dpp(__float_as_int(x), 0x4E, 0xF, 0xF, true);
    x += __int_as_float(i);
    i = __builtin_amdgcn_mov_dpp(__float_as_int(x), 0x141, 0xF, 0xF, true);
    x += __int_as_float(i);
    i = __builtin_amdgcn_mov_dpp(__float_as_int(x), 0x140, 0xF, 0xF, true);
    x += __int_as_float(i);
    return x;
}

// ---- K_pack: Wl/Wr (T-perm, for gemm) + We (cb-perm, for edge_alpha) ----
__global__ __launch_bounds__(256) void pack_kernel(
    const float* __restrict__ Wl, const float* __restrict__ Wr,
    const float* __restrict__ We,
    unsigned short* __restrict__ wlf, unsigned short* __restrict__ wrf,
    unsigned short* __restrict__ wef)
{
    int sid = blockIdx.x * 256 + threadIdx.x;
    const float* W; unsigned short* dst; int s; int col; int k0;
    if (sid < 8192) {
        if (sid < 4096) { W = Wl; dst = wlf; s = sid; }
        else            { W = Wr; dst = wrf; s = sid - 4096; }
        int lane = s & 63;
        int T    = (s >> 6) & 15;
        int kc   = s >> 10;
        col = (lane & 15) * 16 + T;
        k0  = kc * 32 + (lane >> 4) * 8;
    } else if (sid < 9216) {
        W = We; dst = wef; s = sid - 8192;
        int lane = s & 63;
        int nt   = (s >> 6) & 3;
        int cb   = s >> 8;
        col = cb * 64 + (lane & 15) * 4 + nt;
        k0  = (lane >> 4) * 8;
    } else return;
    unsigned short tmp[8];
    #pragma unroll
    for (int j = 0; j < 8; ++j) tmp[j] = f2bf(W[(size_t)(k0 + j) * HC + col]);
    *(uint4*)(dst + (size_t)s * 8) = *(uint4*)tmp;
}

// ---- K1: Y = bf16(X @ W + b) via MFMA, no LDS ----
__global__ __launch_bounds__(256) void gemm_kernel(
    const float* __restrict__ X,
    const unsigned short* __restrict__ wlf, const float* __restrict__ bl,
    const unsigned short* __restrict__ wrf, const float* __restrict__ br,
    unsigned short* __restrict__ Ylb, unsigned short* __restrict__ Yrb)
{
    const unsigned short* wf; const float* b; unsigned short* Yb;
    if (blockIdx.y == 0) { wf = wlf; b = bl; Yb = Ylb; } else { wf = wrf; b = br; Yb = Yrb; }

    const int tid = threadIdx.x, lane = tid & 63;
    const int l15 = lane & 15, l4 = lane >> 4;
    const int r0 = blockIdx.x * 64 + (tid >> 6) * 16;

    int arow = r0 + l15; if (arow >= Nn) arow = Nn - 1;
    short8 af[4];
    #pragma unroll
    for (int kc = 0; kc < 4; ++kc) {
        const f32x4* p = (const f32x4*)(X + (size_t)arow * INC + kc * 32 + l4 * 8);
        f32x4 v0 = p[0], v1 = p[1];
        short8 a;
        a[0]=(short)f2bf(v0.x); a[1]=(short)f2bf(v0.y); a[2]=(short)f2bf(v0.z); a[3]=(short)f2bf(v0.w);
        a[4]=(short)f2bf(v1.x); a[5]=(short)f2bf(v1.y); a[6]=(short)f2bf(v1.z); a[7]=(short)f2bf(v1.w);
        af[kc] = a;
    }

    f32x4 acc[16];
    #pragma unroll
    for (int T = 0; T < 16; ++T) acc[T] = (f32x4){0.f, 0.f, 0.f, 0.f};

    #pragma unroll
    for (int kc = 0; kc < 4; ++kc) {
        #pragma unroll
        for (int T = 0; T < 16; ++T) {
            short8 bf = *(const short8*)(wf + ((size_t)(kc * 16 + T) * 64 + lane) * 8);
            acc[T] = __builtin_amdgcn_mfma_f32_16x16x32_bf16(af[kc], bf, acc[T], 0, 0, 0);
        }
    }

    float bb[16];
    #pragma unroll
    for (int t4 = 0; t4 < 4; ++t4) {
        float4 v = *(const float4*)(b + l15 * 16 + t4 * 4);
        bb[t4*4+0]=v.x; bb[t4*4+1]=v.y; bb[t4*4+2]=v.z; bb[t4*4+3]=v.w;
    }

    #pragma unroll
    for (int r = 0; r < 4; ++r) {
        int orow = r0 + l4 * 4 + r;
        if (orow < Nn) {
            unsigned short o[16];
            #pragma unroll
            for (int T = 0; T < 16; ++T) o[T] = f2bf(acc[T][r] + bb[T]);
            *(uint4*)(Yb + (size_t)orow * HC + l15 * 16)     = *(uint4*)(o);
            *(uint4*)(Yb + (size_t)orow * HC + l15 * 16 + 8) = *(uint4*)(o + 8);
        }
    }
}

// ---- CSR build ----
__global__ __launch_bounds__(256) void zero_kernel(int* __restrict__ deg) {
    int i = blockIdx.x * 256 + threadIdx.x;
    if (i < Nn) deg[i] = 0;
}
__global__ __launch_bounds__(256) void hist_kernel(
    const int* __restrict__ ei, int* __restrict__ deg) {
    int e = blockIdx.x * 256 + threadIdx.x;
    if (e < Ee) atomicAdd(deg + ei[Ee + e], 1);
}
__global__ __launch_bounds__(256) void scan1_kernel(
    const int* __restrict__ deg, int* __restrict__ off, int* __restrict__ bsum) {
    __shared__ int s[256];
    int i = blockIdx.x * 256 + threadIdx.x;
    int v = (i < Nn) ? deg[i] : 0;
    s[threadIdx.x] = v;
    __syncthreads();
    #pragma unroll
    for (int d = 1; d < 256; d <<= 1) {
        int t = (threadIdx.x >= d) ? s[threadIdx.x - d] : 0;
        __syncthreads();
        s[threadIdx.x] += t;
        __syncthreads();
    }
    if (i < Nn) off[i] = s[threadIdx.x] - v;
    if (threadIdx.x == 255) bsum[blockIdx.x] = s[255];
}
__global__ __launch_bounds__(256) void scan2_kernel(int* __restrict__ bsum) {
    __shared__ int s[256];
    int v = (threadIdx.x < NB) ? bsum[threadIdx.x] : 0;
    s[threadIdx.x] = v;
    __syncthreads();
    #pragma unroll
    for (int d = 1; d < 256; d <<= 1) {
        int t = (threadIdx.x >= d) ? s[threadIdx.x - d] : 0;
        __syncthreads();
        s[threadIdx.x] += t;
        __syncthreads();
    }
    if (threadIdx.x < NB) bsum[threadIdx.x] = s[threadIdx.x] - v;
}
__global__ __launch_bounds__(256) void scan3_kernel(
    int* __restrict__ off, const int* __restrict__ bsum, int* __restrict__ cur) {
    int i = blockIdx.x * 256 + threadIdx.x;
    if (i < Nn) {
        int o = off[i] + bsum[blockIdx.x];
        off[i] = o;
        cur[i] = o;
    }
}
__global__ __launch_bounds__(256) void scatter_kernel(
    const int* __restrict__ ei, int* __restrict__ cur,
    int* __restrict__ csr_e, int* __restrict__ csr_s, int* __restrict__ csr_d) {
    int e = blockIdx.x * 256 + threadIdx.x;
    if (e >= Ee) return;
    int d = ei[Ee + e];
    int pos = atomicAdd(cur + d, 1);
    csr_e[pos] = e;
    csr_s[pos] = ei[e];
    csr_d[pos] = d;
}

// ---- K2: per-edge logits via MFMA bf16, CSR-ORDERED positions ----
// Tile = 32 consecutive CSR positions (dst-sorted): xrb[dst] gathers hit
// L1/L2 (deg~10 edges share the row). ea rows gathered via csr_e (same
// cache-line count as sequential). alpha written at POSITION order ->
// node_aggr reads it fully coalesced with no csr_e indirection.
__global__ __launch_bounds__(256) void edge_alpha_kernel(
    const unsigned short* __restrict__ xlb, const unsigned short* __restrict__ xrb,
    const int* __restrict__ csr_e, const int* __restrict__ csr_s,
    const int* __restrict__ csr_d, const float* __restrict__ ea,
    const unsigned short* __restrict__ wef, const float* __restrict__ att,
    float* __restrict__ alpha)
{
    const int tid  = threadIdx.x;
    const int lane = tid & 63;
    const int l15  = lane & 15, l4 = lane >> 4;
    const int p0   = blockIdx.x * 128 + (tid >> 6) * 32;

    // A-frags: rows = csr_e[p0+mt*16+l15], nontemporal (each ea row read once)
    short8 afrag[2];
    #pragma unroll
    for (int mt = 0; mt < 2; ++mt) {
        int p = p0 + mt * 16 + l15;
        if (p >= Ee) p = Ee - 1;
        int e = csr_e[p];
        const f32x4* pp = (const f32x4*)(ea + (size_t)e * EDIM + l4 * 8);
        f32x4 v0 = __builtin_nontemporal_load(pp);
        f32x4 v1 = __builtin_nontemporal_load(pp + 1);
        short8 a;
        a[0]=(short)f2bf(v0.x); a[1]=(short)f2bf(v0.y); a[2]=(short)f2bf(v0.z); a[3]=(short)f2bf(v0.w);
        a[4]=(short)f2bf(v1.x); a[5]=(short)f2bf(v1.y); a[6]=(short)f2bf(v1.z); a[7]=(short)f2bf(v1.w);
        afrag[mt] = a;
    }

    unsigned soff[8], doff[8];
    #pragma unroll
    for (int mt = 0; mt < 2; ++mt)
        #pragma unroll
        for (int r = 0; r < 4; ++r) {
            int idx = mt * 4 + r;
            int p = p0 + mt * 16 + l4 * 4 + r;
            int pc = (p < Ee) ? p : Ee - 1;
            soff[idx] = (unsigned)csr_s[pc] * (unsigned)HC;
            doff[idx] = (unsigned)csr_d[pc] * (unsigned)HC;
        }

    #pragma unroll 1
    for (int cb = 0; cb < 4; ++cb) {
        short8 bfrag[4];
        #pragma unroll
        for (int nt = 0; nt < 4; ++nt)
            bfrag[nt] = *(const short8*)(wef + ((size_t)(cb * 4 + nt) * 64 + lane) * 8);

        f32x4 acc[2][4];
        const f32x4 z = {0.f, 0.f, 0.f, 0.f};
        #pragma unroll
        for (int mt = 0; mt < 2; ++mt)
            #pragma unroll
            for (int nt = 0; nt < 4; ++nt)
                acc[mt][nt] = __builtin_amdgcn_mfma_f32_16x16x32_bf16(
                    afrag[mt], bfrag[nt], z, 0, 0, 0);

        float4 atv = *(const float4*)(att + cb * 64 + l15 * 4);

        #pragma unroll
        for (int mt = 0; mt < 2; ++mt) {
            #pragma unroll
            for (int r = 0; r < 4; ++r) {
                const int idx = mt * 4 + r;
                const unsigned c = (unsigned)(cb * 64 + l15 * 4);
                ushort4 gl4 = *(const ushort4*)(xlb + soff[idx] + c);
                ushort4 gr4 = *(const ushort4*)(xrb + doff[idx] + c);
                float m0 = acc[mt][0][r] + bf2f(gl4.x) + bf2f(gr4.x);
                float m1 = acc[mt][1][r] + bf2f(gl4.y) + bf2f(gr4.y);
                float m2 = acc[mt][2][r] + bf2f(gl4.z) + bf2f(gr4.z);
                float m3 = acc[mt][3][r] + bf2f(gl4.w) + bf2f(gr4.w);
                m0 = fmaxf(m0, NEG * m0);
                m1 = fmaxf(m1, NEG * m1);
                m2 = fmaxf(m2, NEG * m2);
                m3 = fmaxf(m3, NEG * m3);
                float p;
                p = atv.x * m0;
                p = fmaf(atv.y, m1, p);
                p = fmaf(atv.z, m2, p);
                p = fmaf(atv.w, m3, p);
                p = row_sum16(p);
                int pp = p0 + mt * 16 + l4 * 4 + r;
                if (l15 == 0 && pp < Ee)
                    alpha[(size_t)pp * 4 + cb] = p;
            }
        }
    }
}

// ---- K4: fused per-node softmax + aggregation, ONE WAVE PER NODE ----
// alpha is position-ordered: staging load is fully coalesced, no csr_e.
__global__ __launch_bounds__(256) void node_aggr_kernel(
    const unsigned short* __restrict__ xlb,
    const int* __restrict__ csr_s,
    const float* __restrict__ alpha, const int* __restrict__ off,
    const int* __restrict__ deg, const float* __restrict__ bias,
    float* __restrict__ out)
{
    __shared__ float shw[4][64];
    __shared__ int   shs[4][16];
    const int lane = threadIdx.x & 63;
    const int wv   = threadIdx.x >> 6;
    const int n    = blockIdx.x * 4 + wv;
    if (n >= Nn) return;

    const int start = off[n];
    const int len   = deg[n];

    if (len == 0) {
        if (lane < 16) {
            float4 b4 = *(const float4*)(bias + lane * 4);
            *(float4*)(out + (size_t)n * OUTC + lane * 4) = b4;
        }
        return;
    }

    const int eidx = lane >> 2;     // staging: edge slot 0..15
    const int hagg = lane >> 4;     // aggregation: head of this lane's quad

    float m = -3.4e38f, d = 0.f;
    float4 acc = make_float4(0.f, 0.f, 0.f, 0.f);

    for (int c0 = 0; c0 < len; c0 += 16) {
        int cl = len - c0; if (cl > 16) cl = 16;
        // coalesced: lane reads alpha[(start+c0)*4 + lane]
        float a = (eidx < cl) ? alpha[(size_t)(start + c0) * 4 + lane] : -3.4e38f;
        if (lane < cl) shs[wv][lane] = csr_s[start + c0 + lane];
        // per-head chunk max (stride-4 class reduce, result uniform per class)
        float cm = a;
        cm = fmaxf(cm, __shfl_xor(cm, 4, 64));
        cm = fmaxf(cm, __shfl_xor(cm, 8, 64));
        cm = fmaxf(cm, __shfl_xor(cm, 16, 64));
        cm = fmaxf(cm, __shfl_xor(cm, 32, 64));
        float mn = fmaxf(m, cm);
        float sc = __expf(m - mn);          // 1 if unchanged; 0 on first chunk
        float w  = (eidx < cl) ? __expf(a - mn) : 0.f;
        float ws = w;
        ws += __shfl_xor(ws, 4, 64);
        ws += __shfl_xor(ws, 8, 64);
        ws += __shfl_xor(ws, 16, 64);
        ws += __shfl_xor(ws, 32, 64);
        d = d * sc + ws;
        m = mn;
        shw[wv][lane] = w;                  // slot = edge*4 + head
        float sca = __shfl(sc, hagg, 64);
        acc.x *= sca; acc.y *= sca; acc.z *= sca; acc.w *= sca;
        #pragma unroll 4
        for (int i = 0; i < cl; ++i) {
            int   si = shs[wv][i];
            float wi = shw[wv][i * 4 + hagg];
            ushort4 g = *(const ushort4*)(xlb + (size_t)si * HC + lane * 4);
            acc.x = fmaf(wi, bf2f(g.x), acc.x);
            acc.y = fmaf(wi, bf2f(g.y), acc.y);
            acc.z = fmaf(wi, bf2f(g.z), acc.z);
            acc.w = fmaf(wi, bf2f(g.w), acc.w);
        }
    }

    float dh = __shfl(d, hagg, 64);
    float di = 1.f / dh;
    float4 r;
    r.x = acc.x * di; r.y = acc.y * di; r.z = acc.z * di; r.w = acc.w * di;
    r.x += __shfl_xor(r.x, 16, 64); r.y += __shfl_xor(r.y, 16, 64);
    r.z += __shfl_xor(r.z, 16, 64); r.w += __shfl_xor(r.w, 16, 64);
    r.x += __shfl_xor(r.x, 32, 64); r.y += __shfl_xor(r.y, 32, 64);
    r.z += __shfl_xor(r.z, 32, 64); r.w += __shfl_xor(r.w, 32, 64);
    if (lane < 16) {
        float4 b4 = *(const float4*)(bias + lane * 4);
        float4 o = make_float4(b4.x + 0.25f * r.x, b4.y + 0.25f * r.y,
                               b4.z + 0.25f * r.z, b4.w + 0.25f * r.w);
        *(float4*)(out + (size_t)n * OUTC + lane * 4) = o;
    }
}

extern "C" void kernel_launch(void* const* d_in, const int* in_sizes, int n_in,
                              void* d_out, int out_size, void* d_ws, size_t ws_size,
                              hipStream_t stream)
{
    const float* x    = (const float*)d_in[0];
    const int*   ei   = (const int*)d_in[1];
    const float* ea   = (const float*)d_in[2];
    const float* Wl   = (const float*)d_in[3];
    const float* bl   = (const float*)d_in[4];
    const float* Wr   = (const float*)d_in[5];
    const float* br   = (const float*)d_in[6];
    const float* We   = (const float*)d_in[7];
    const float* att  = (const float*)d_in[8];
    const float* bias = (const float*)d_in[9];
    float* out = (float*)d_out;

    // workspace layout (~66 MB)
    unsigned short* xlb   = (unsigned short*)d_ws;                 // N*256 bf16
    unsigned short* xrb   = xlb + (size_t)Nn * HC;                 // N*256 bf16
    float*          alpha = (float*)(xrb + (size_t)Nn * HC);       // E*4 f32 (CSR order)
    unsigned short* wef   = (unsigned short*)(alpha + (size_t)Ee * 4); // 8192 bf16
    unsigned short* wlf   = wef + 8192;                            // 32768 bf16
    unsigned short* wrf   = wlf + 32768;                           // 32768 bf16
    int*            deg   = (int*)(wrf + 32768);                   // N
    int*            off   = deg + Nn;                              // N
    int*            cur   = off + Nn;                              // N
    int*            bsum  = cur + Nn;                              // NB
    int*            csr_e = bsum + 256;                            // E
    int*            csr_s = csr_e + Ee;                            // E
    int*            csr_d = csr_s + Ee;                            // E

    pack_kernel<<<36, 256, 0, stream>>>(Wl, Wr, We, wlf, wrf, wef);
    gemm_kernel<<<dim3((Nn + 63) / 64, 2), 256, 0, stream>>>(x, wlf, bl, wrf, br, xlb, xrb);
    zero_kernel<<<NB, 256, 0, stream>>>(deg);
    hist_kernel<<<(Ee + 255) / 256, 256, 0, stream>>>(ei, deg);
    scan1_kernel<<<NB, 256, 0, stream>>>(deg, off, bsum);
    scan2_kernel<<<1, 256, 0, stream>>>(bsum);
    scan3_kernel<<<NB, 256, 0, stream>>>(off, bsum, cur);
    scatter_kernel<<<(Ee + 255) / 256, 256, 0, stream>>>(ei, cur, csr_e, csr_s, csr_d);
    edge_alpha_kernel<<<(Ee + 127) / 128, 256, 0, stream>>>(xlb, xrb, csr_e, csr_s, csr_d, ea, wef, att, alpha);
    node_aggr_kernel<<<(Nn + 3) / 4, 256, 0, stream>>>(xlb, csr_s, alpha, off, deg, bias, out);
}